// Round 1
// baseline (311.312 us; speedup 1.0000x reference)
//
#include <hip/hip_runtime.h>

typedef _Float16 f16;
typedef _Float16 f16x4 __attribute__((ext_vector_type(4)));
typedef _Float16 f16x8 __attribute__((ext_vector_type(8)));
typedef float    f32x4 __attribute__((ext_vector_type(4)));
typedef int      i32x4 __attribute__((ext_vector_type(4)));

#define NHEADS 16
#define DK 64
#define BATCH 2
#define SEQ 2048
#define DMODEL 1024
#define MTOT (BATCH*SEQ)          // 4096
#define NQKV (3*DMODEL)           // 3072
#define ATT_SCALE 0.125f
#define MASK_FILL -10000.0f

__device__ inline f16x8 ld_f16x8_g(const f16* p) {
  return __builtin_bit_cast(f16x8, *reinterpret_cast<const i32x4*>(p));
}

// ---------------- convert f32 -> f16, elementwise (n % 4 == 0) ----------------
__global__ void k_cvt(const float* __restrict__ in, f16* __restrict__ out, int n) {
  int i = (blockIdx.x * blockDim.x + threadIdx.x) * 4;
  if (i >= n) return;
  float4 v = *reinterpret_cast<const float4*>(in + i);
  f16x4 o = { (f16)v.x, (f16)v.y, (f16)v.z, (f16)v.w };
  *reinterpret_cast<f16x4*>(out + i) = o;
}

// ------- transpose + convert: in f32 [K][N] -> out f16 [N][K] (K,N % 32 == 0) -------
__global__ void k_tcvt(const float* __restrict__ in, f16* __restrict__ out, int K, int N) {
  __shared__ float tile[32][33];
  int k0 = blockIdx.y * 32, n0 = blockIdx.x * 32;
  int tx = threadIdx.x, ty = threadIdx.y;   // block (32,8)
  #pragma unroll
  for (int i = 0; i < 4; ++i)
    tile[ty + 8*i][tx] = in[(size_t)(k0 + ty + 8*i) * N + n0 + tx];
  __syncthreads();
  #pragma unroll
  for (int i = 0; i < 4; ++i)
    out[(size_t)(n0 + ty + 8*i) * K + k0 + tx] = (f16)tile[tx][ty + 8*i];
}

// ---------------- GEMM: C[M,N] = A[M,K](f16) * Bt[N,K]^T(f16) + bias ----------------
// 128x128 tile, BK=64, 4 waves (2x2), each wave 64x64 via 4x4 MFMA 16x16x32 frags.
// EPI=0: scatter to Q (scaled), K [b,h,s,d], V^T [b,h,d,s] (f16).
// EPI=1: write f32 to outf.
template<int EPI>
__global__ __launch_bounds__(256, 2) void k_gemm(
    const f16* __restrict__ A, const f16* __restrict__ Bt,
    const float* __restrict__ bias,
    f16* __restrict__ qo, f16* __restrict__ ko, f16* __restrict__ vto,
    float* __restrict__ outf, int M, int N, int K)
{
  __shared__ f16 As[128][72];
  __shared__ f16 Bs[128][72];
  const int m0 = blockIdx.y * 128, n0 = blockIdx.x * 128;
  const int t = threadIdx.x;
  const int l = t & 63, w = t >> 6;
  const int wr = w >> 1, wc = w & 1;
  const int lc = l & 15, lk = (l >> 4) * 8;

  f32x4 acc[4][4] = {};

  for (int kt = 0; kt < K; kt += 64) {
    #pragma unroll
    for (int it = 0; it < 4; ++it) {
      int idx = it * 256 + t;
      int row = idx >> 3, c8 = (idx & 7) * 8;
      *reinterpret_cast<i32x4*>(&As[row][c8]) =
        *reinterpret_cast<const i32x4*>(A + (size_t)(m0 + row) * K + kt + c8);
      *reinterpret_cast<i32x4*>(&Bs[row][c8]) =
        *reinterpret_cast<const i32x4*>(Bt + (size_t)(n0 + row) * K + kt + c8);
    }
    __syncthreads();
    #pragma unroll
    for (int ks = 0; ks < 64; ks += 32) {
      f16x8 af[4], bf[4];
      #pragma unroll
      for (int i = 0; i < 4; ++i)
        af[i] = __builtin_bit_cast(f16x8, *reinterpret_cast<i32x4*>(&As[wr*64 + i*16 + lc][ks + lk]));
      #pragma unroll
      for (int j = 0; j < 4; ++j)
        bf[j] = __builtin_bit_cast(f16x8, *reinterpret_cast<i32x4*>(&Bs[wc*64 + j*16 + lc][ks + lk]));
      #pragma unroll
      for (int i = 0; i < 4; ++i)
        #pragma unroll
        for (int j = 0; j < 4; ++j)
          acc[i][j] = __builtin_amdgcn_mfma_f32_16x16x32_f16(af[i], bf[j], acc[i][j], 0, 0, 0);
    }
    __syncthreads();
  }

  const int lr4 = (l >> 4) * 4;   // C/D: row = (l>>4)*4 + r, col = l&15
  #pragma unroll
  for (int i = 0; i < 4; ++i) {
    #pragma unroll
    for (int j = 0; j < 4; ++j) {
      int col = n0 + wc*64 + j*16 + lc;
      float bv = bias[col];
      #pragma unroll
      for (int r = 0; r < 4; ++r) {
        int row = m0 + wr*64 + i*16 + lr4 + r;
        float v = acc[i][j][r] + bv;
        if (EPI == 0) {
          int which = col >> 10, h = (col >> 6) & 15, d = col & 63;
          int b = row >> 11, s = row & (SEQ - 1);
          size_t bh = (size_t)(b * NHEADS + h);
          if (which == 0)      qo[(bh * SEQ + s) * DK + d] = (f16)(v * ATT_SCALE);
          else if (which == 1) ko[(bh * SEQ + s) * DK + d] = (f16)v;
          else                 vto[(bh * DK + d) * SEQ + s] = (f16)v;
        } else {
          outf[(size_t)row * N + col] = v;
        }
      }
    }
  }
}

// ---------------- flash attention ----------------
// grid: 1024 blocks = 32 (b,h) * 32 q-tiles of 64; 4 waves/block, wave owns 16 q rows.
// K,V^T fragments read straight from global (L2-resident, 256KB/head).
__global__ __launch_bounds__(256) void k_attn(
    const f16* __restrict__ Q, const f16* __restrict__ K,
    const f16* __restrict__ Vt, const int* __restrict__ mask,
    f16* __restrict__ ctx)
{
  __shared__ f16 Plds[4][16][72];   // per-wave P tile (16 q x 64 k), padded
  const int bh = blockIdx.x >> 5, qb = blockIdx.x & 31;
  const int b = bh >> 4, h = bh & (NHEADS - 1);
  const int t = threadIdx.x, l = t & 63, w = t >> 6;
  const int lc = l & 15, lk = (l >> 4) * 8, lr4 = (l >> 4) * 4;
  const int q0 = qb * 64 + w * 16;

  const f16* Qp = Q + (size_t)bh * SEQ * DK;
  const f16* Kp = K + (size_t)bh * SEQ * DK;
  const f16* Vp = Vt + (size_t)bh * DK * SEQ;
  const int* mp = mask + b * SEQ;

  f16x8 qa[2];
  #pragma unroll
  for (int s = 0; s < 2; ++s)
    qa[s] = ld_f16x8_g(Qp + (size_t)(q0 + lc) * DK + s*32 + lk);

  f32x4 o[4] = {};
  float mrow[4] = {-1e30f, -1e30f, -1e30f, -1e30f};
  float lsum[4] = {0.f, 0.f, 0.f, 0.f};

  for (int kt = 0; kt < SEQ; kt += 64) {
    // S = Q K^T (pre-scaled Q), 16 x 64 per wave
    f32x4 st[4];
    #pragma unroll
    for (int c = 0; c < 4; ++c) {
      const f16* kr = Kp + (size_t)(kt + c*16 + lc) * DK;
      f32x4 z = {};
      z = __builtin_amdgcn_mfma_f32_16x16x32_f16(qa[0], ld_f16x8_g(kr + lk), z, 0, 0, 0);
      st[c] = __builtin_amdgcn_mfma_f32_16x16x32_f16(qa[1], ld_f16x8_g(kr + 32 + lk), z, 0, 0, 0);
      int mv = mp[kt + c*16 + lc];
      if (mv == 0) {
        #pragma unroll
        for (int r = 0; r < 4; ++r) st[c][r] = MASK_FILL;
      }
    }
    // online softmax: row = lr4 + r, row-reduce over 16-lane group
    #pragma unroll
    for (int r = 0; r < 4; ++r) {
      float v = fmaxf(fmaxf(st[0][r], st[1][r]), fmaxf(st[2][r], st[3][r]));
      v = fmaxf(v, __shfl_xor(v, 1));
      v = fmaxf(v, __shfl_xor(v, 2));
      v = fmaxf(v, __shfl_xor(v, 4));
      v = fmaxf(v, __shfl_xor(v, 8));
      float mn = fmaxf(mrow[r], v);
      float f = __expf(mrow[r] - mn);
      mrow[r] = mn;
      lsum[r] *= f;
      #pragma unroll
      for (int c = 0; c < 4; ++c) o[c][r] *= f;
    }
    #pragma unroll
    for (int c = 0; c < 4; ++c)
      #pragma unroll
      for (int r = 0; r < 4; ++r) {
        float p = __expf(st[c][r] - mrow[r]);
        lsum[r] += p;
        Plds[w][lr4 + r][c*16 + lc] = (f16)p;
      }
    // O += P V  (P via LDS transpose to A-frag layout; V^T rows are contiguous)
    #pragma unroll
    for (int s = 0; s < 2; ++s) {
      f16x8 pa = __builtin_bit_cast(f16x8,
          *reinterpret_cast<i32x4*>(&Plds[w][lc][s*32 + lk]));
      #pragma unroll
      for (int c = 0; c < 4; ++c) {
        f16x8 vb = ld_f16x8_g(Vp + (size_t)(c*16 + lc) * SEQ + kt + s*32 + lk);
        o[c] = __builtin_amdgcn_mfma_f32_16x16x32_f16(pa, vb, o[c], 0, 0, 0);
      }
    }
  }

  // final row sums + write context [b, s, h*64+d] as f16
  #pragma unroll
  for (int r = 0; r < 4; ++r) {
    float v = lsum[r];
    v += __shfl_xor(v, 1);
    v += __shfl_xor(v, 2);
    v += __shfl_xor(v, 4);
    v += __shfl_xor(v, 8);
    lsum[r] = v;
  }
  #pragma unroll
  for (int c = 0; c < 4; ++c)
    #pragma unroll
    for (int r = 0; r < 4; ++r) {
      int qrow = q0 + lr4 + r;
      int d = c*16 + lc;
      float val = o[c][r] / lsum[r];
      ctx[((size_t)(b * SEQ + qrow)) * DMODEL + h * DK + d] = (f16)val;
    }
}

extern "C" void kernel_launch(void* const* d_in, const int* in_sizes, int n_in,
                              void* d_out, int out_size, void* d_ws, size_t ws_size,
                              hipStream_t stream) {
  const float* x    = (const float*)d_in[0];
  const int*   mask = (const int*)d_in[1];
  const float* Wqkv = (const float*)d_in[2];
  const float* bqkv = (const float*)d_in[3];
  const float* Wout = (const float*)d_in[4];
  const float* bout = (const float*)d_in[5];
  float* out = (float*)d_out;

  // workspace layout (all f16), total 48 MiB
  const size_t SZ_X    = (size_t)MTOT * DMODEL * 2;     // 8 MiB
  const size_t SZ_WQKV = (size_t)NQKV * DMODEL * 2;     // 6 MiB
  const size_t SZ_WOUT = (size_t)DMODEL * DMODEL * 2;   // 2 MiB
  const size_t SZ_QKV  = (size_t)BATCH * NHEADS * SEQ * DK * 2; // 8 MiB each
  const size_t NEED = SZ_X + SZ_WQKV + SZ_WOUT + 3*SZ_QKV + SZ_X;
  if (ws_size < NEED) return;   // avoid corrupting memory if ws too small

  char* p = (char*)d_ws;
  f16* xh    = (f16*)p; p += SZ_X;
  f16* Wqkvt = (f16*)p; p += SZ_WQKV;
  f16* Woutt = (f16*)p; p += SZ_WOUT;
  f16* Qh    = (f16*)p; p += SZ_QKV;
  f16* Kh    = (f16*)p; p += SZ_QKV;
  f16* Vth   = (f16*)p; p += SZ_QKV;
  f16* ctx   = (f16*)p; p += SZ_X;

  // 1) conversions
  k_cvt<<<(MTOT*DMODEL)/(256*4), 256, 0, stream>>>(x, xh, MTOT*DMODEL);
  k_tcvt<<<dim3(NQKV/32, DMODEL/32), dim3(32,8), 0, stream>>>(Wqkv, Wqkvt, DMODEL, NQKV);
  k_tcvt<<<dim3(DMODEL/32, DMODEL/32), dim3(32,8), 0, stream>>>(Wout, Woutt, DMODEL, DMODEL);

  // 2) QKV projection, scatter to Q/K/V^T
  k_gemm<0><<<dim3(NQKV/128, MTOT/128), 256, 0, stream>>>(
      xh, Wqkvt, bqkv, Qh, Kh, Vth, nullptr, MTOT, NQKV, DMODEL);

  // 3) flash attention
  k_attn<<<BATCH*NHEADS*(SEQ/64), 256, 0, stream>>>(Qh, Kh, Vth, mask, ctx);

  // 4) output projection (f32 out)
  k_gemm<1><<<dim3(DMODEL/128, MTOT/128), 256, 0, stream>>>(
      ctx, Woutt, bout, nullptr, nullptr, nullptr, out, MTOT, DMODEL, DMODEL);
}

// Round 3
// 154.211 us; speedup vs baseline: 2.0187x; 2.0187x over previous
//
#include <hip/hip_runtime.h>

typedef _Float16 f16;
typedef _Float16 f16x2 __attribute__((ext_vector_type(2)));
typedef _Float16 f16x4 __attribute__((ext_vector_type(4)));
typedef _Float16 f16x8 __attribute__((ext_vector_type(8)));
typedef float    f32x4 __attribute__((ext_vector_type(4)));
typedef int      i32x4 __attribute__((ext_vector_type(4)));

#define NHEADS 16
#define DK 64
#define BATCH 2
#define SEQ 2048
#define DMODEL 1024
#define MTOT (BATCH*SEQ)          // 4096
#define NQKV (3*DMODEL)           // 3072
#define LOG2E 1.44269504f
#define QSCALE (0.125f * LOG2E)   // fold 1/sqrt(dk) and log2(e) into Q
#define MASKVAL (-10000.0f * LOG2E)

__device__ inline f16x8 ld_f16x8_g(const f16* p) {
  return __builtin_bit_cast(f16x8, *reinterpret_cast<const i32x4*>(p));
}

__device__ inline f16x2 cvt_pk(float a, float b) {
  return __builtin_bit_cast(f16x2, __builtin_amdgcn_cvt_pkrtz(a, b));
}

__device__ inline void gl_lds16(const void* g, void* l) {
  __builtin_amdgcn_global_load_lds(
      (const __attribute__((address_space(1))) unsigned int*)g,
      (__attribute__((address_space(3))) unsigned int*)l, 16, 0, 0);
}

// ---------------- convert f32 -> f16, elementwise (n % 4 == 0) ----------------
__global__ void k_cvt(const float* __restrict__ in, f16* __restrict__ out, int n) {
  int i = (blockIdx.x * blockDim.x + threadIdx.x) * 4;
  if (i >= n) return;
  float4 v = *reinterpret_cast<const float4*>(in + i);
  f16x4 o = { (f16)v.x, (f16)v.y, (f16)v.z, (f16)v.w };
  *reinterpret_cast<f16x4*>(out + i) = o;
}

// ------- transpose + convert: in f32 [K][N] -> out f16 [N][K] (K,N % 32 == 0) -------
__global__ void k_tcvt(const float* __restrict__ in, f16* __restrict__ out, int K, int N) {
  __shared__ float tile[32][33];
  int k0 = blockIdx.y * 32, n0 = blockIdx.x * 32;
  int tx = threadIdx.x, ty = threadIdx.y;   // block (32,8)
  #pragma unroll
  for (int i = 0; i < 4; ++i)
    tile[ty + 8*i][tx] = in[(size_t)(k0 + ty + 8*i) * N + n0 + tx];
  __syncthreads();
  #pragma unroll
  for (int i = 0; i < 4; ++i)
    out[(size_t)(n0 + ty + 8*i) * K + k0 + tx] = (f16)tile[tx][ty + 8*i];
}

// ---------------- GEMM: C[M,N] = A[M,K](f16) * Bt[N,K]^T(f16) + bias ----------------
template<int EPI>
__global__ __launch_bounds__(256, 2) void k_gemm(
    const f16* __restrict__ A, const f16* __restrict__ Bt,
    const float* __restrict__ bias,
    f16* __restrict__ qo, f16* __restrict__ ko, f16* __restrict__ vto,
    float* __restrict__ outf, int M, int N, int K)
{
  __shared__ f16 As[128][72];
  __shared__ f16 Bs[128][72];
  const int m0 = blockIdx.y * 128, n0 = blockIdx.x * 128;
  const int t = threadIdx.x;
  const int l = t & 63, w = t >> 6;
  const int wr = w >> 1, wc = w & 1;
  const int lc = l & 15, lk = (l >> 4) * 8;

  f32x4 acc[4][4] = {};

  for (int kt = 0; kt < K; kt += 64) {
    #pragma unroll
    for (int it = 0; it < 4; ++it) {
      int idx = it * 256 + t;
      int row = idx >> 3, c8 = (idx & 7) * 8;
      *reinterpret_cast<i32x4*>(&As[row][c8]) =
        *reinterpret_cast<const i32x4*>(A + (size_t)(m0 + row) * K + kt + c8);
      *reinterpret_cast<i32x4*>(&Bs[row][c8]) =
        *reinterpret_cast<const i32x4*>(Bt + (size_t)(n0 + row) * K + kt + c8);
    }
    __syncthreads();
    #pragma unroll
    for (int ks = 0; ks < 64; ks += 32) {
      f16x8 af[4], bf[4];
      #pragma unroll
      for (int i = 0; i < 4; ++i)
        af[i] = __builtin_bit_cast(f16x8, *reinterpret_cast<i32x4*>(&As[wr*64 + i*16 + lc][ks + lk]));
      #pragma unroll
      for (int j = 0; j < 4; ++j)
        bf[j] = __builtin_bit_cast(f16x8, *reinterpret_cast<i32x4*>(&Bs[wc*64 + j*16 + lc][ks + lk]));
      #pragma unroll
      for (int i = 0; i < 4; ++i)
        #pragma unroll
        for (int j = 0; j < 4; ++j)
          acc[i][j] = __builtin_amdgcn_mfma_f32_16x16x32_f16(af[i], bf[j], acc[i][j], 0, 0, 0);
    }
    __syncthreads();
  }

  const int lr4 = (l >> 4) * 4;   // C/D: row = (l>>4)*4 + r, col = l&15
  #pragma unroll
  for (int i = 0; i < 4; ++i) {
    #pragma unroll
    for (int j = 0; j < 4; ++j) {
      int col = n0 + wc*64 + j*16 + lc;
      float bv = bias[col];
      #pragma unroll
      for (int r = 0; r < 4; ++r) {
        int row = m0 + wr*64 + i*16 + lr4 + r;
        float v = acc[i][j][r] + bv;
        if (EPI == 0) {
          int which = col >> 10, h = (col >> 6) & 15, d = col & 63;
          int b = row >> 11, s = row & (SEQ - 1);
          size_t bh = (size_t)(b * NHEADS + h);
          if (which == 0)      qo[(bh * SEQ + s) * DK + d] = (f16)(v * QSCALE);
          else if (which == 1) ko[(bh * SEQ + s) * DK + d] = (f16)v;
          else                 vto[(bh * DK + d) * SEQ + s] = (f16)v;
        } else {
          outf[(size_t)row * N + col] = v;
        }
      }
    }
  }
}

// ---------------- flash attention v2 ----------------
// 512 blocks = 32 (b,h) * 16 q-blocks of 128; 4 waves, wave owns 32 q rows.
// K/V^T double-buffered in LDS via global_load_lds (swizzled source, T21).
// Swapped layouts: S^T = mfma(K,Q)  (q lane-local), O^T = mfma(V^T, P^T).
__global__ __launch_bounds__(256, 2) void k_attn2(
    const f16* __restrict__ Q, const f16* __restrict__ K,
    const f16* __restrict__ Vt, const int* __restrict__ mask,
    f16* __restrict__ ctx)
{
  __shared__ f16 Kb[2][64][64];
  __shared__ f16 Vb[2][64][64];
  __shared__ f16 Pl[4][32][72];

  const int bh = blockIdx.x >> 4, qb = blockIdx.x & 15;
  const int b  = bh >> 4, h = bh & (NHEADS - 1);
  const int t = threadIdx.x, l = t & 63, w = t >> 6;
  const int lc = l & 15, g = l >> 4;
  const int q0 = qb * 128 + w * 32;

  const f16* Qp = Q + (size_t)bh * SEQ * DK;
  const f16* Kp = K + (size_t)bh * SEQ * DK;
  const f16* Vp = Vt + (size_t)bh * DK * SEQ;
  const int* mp = mask + b * SEQ;

  // Q B-frags (col = q = lc, k-dim = d), kept in regs for the whole kernel
  f16x8 qf[2][2];
  #pragma unroll
  for (int qt = 0; qt < 2; ++qt)
    #pragma unroll
    for (int s = 0; s < 2; ++s)
      qf[qt][s] = ld_f16x8_g(Qp + (size_t)(q0 + qt*16 + lc) * DK + s*32 + g*8);

  f32x4 o[2][4] = {};                      // O^T acc: [q-tile][d-tile]
  float mrow[2] = {-3e38f, -3e38f};
  float lsum[2] = {0.f, 0.f};

  const int srow = l >> 3;                 // staging: row within 8-row stripe
  const int ssl  = ((l & 7) ^ srow) * 16;  // inverse-swizzled source 16B slot

  auto do_stage = [&](int buf, int kt) {
    #pragma unroll
    for (int p = 0; p < 2; ++p) {
      int r = p*32 + w*8 + srow;
      gl_lds16((const char*)Kp + (size_t)(kt + r) * (DK*2) + ssl,
               &Kb[buf][p*32 + w*8][0]);
      gl_lds16((const char*)Vp + (size_t)r * (SEQ*2) + (size_t)kt*2 + ssl,
               &Vb[buf][p*32 + w*8][0]);
    }
  };

  do_stage(0, 0);
  __syncthreads();

  int cur = 0;
  for (int it = 0; it < SEQ/64; ++it) {
    const int kt = it * 64;
    if (it + 1 < SEQ/64) do_stage(cur ^ 1, kt + 64);

    // --- S^T = K * Q^T  (rows = k, cols = q) ---
    f32x4 p[2][4] = {};
    #pragma unroll
    for (int c = 0; c < 4; ++c) {
      const char* kbase = (const char*)&Kb[cur][0][0] + (c*16 + lc) * 128;
      f16x8 k0 = *(const f16x8*)(kbase + ((g*16)      ^ ((lc & 7) << 4)));
      f16x8 k1 = *(const f16x8*)(kbase + ((64 + g*16) ^ ((lc & 7) << 4)));
      #pragma unroll
      for (int qt = 0; qt < 2; ++qt) {
        p[qt][c] = __builtin_amdgcn_mfma_f32_16x16x32_f16(k0, qf[qt][0], p[qt][c], 0, 0, 0);
        p[qt][c] = __builtin_amdgcn_mfma_f32_16x16x32_f16(k1, qf[qt][1], p[qt][c], 0, 0, 0);
      }
    }

    // --- mask: replace masked k-rows with MASKVAL (lane's k = 16c + 4g + r) ---
    #pragma unroll
    for (int c = 0; c < 4; ++c) {
      int4 mv = *(const int4*)(mp + kt + c*16 + g*4);
      const int mi[4] = {mv.x, mv.y, mv.z, mv.w};
      #pragma unroll
      for (int r = 0; r < 4; ++r)
        if (mi[r] == 0) { p[0][c][r] = MASKVAL; p[1][c][r] = MASKVAL; }
    }

    // --- online softmax (per q-tile; defer-max T13, THR=8 on log2 scale) ---
    float mx[2];
    #pragma unroll
    for (int qt = 0; qt < 2; ++qt) {
      f32x4 m4 = p[qt][0];
      #pragma unroll
      for (int c = 1; c < 4; ++c)
        #pragma unroll
        for (int r = 0; r < 4; ++r) m4[r] = fmaxf(m4[r], p[qt][c][r]);
      mx[qt] = fmaxf(fmaxf(m4[0], m4[1]), fmaxf(m4[2], m4[3]));
    }

    if (!__all(mx[0] <= mrow[0] + 8.f && mx[1] <= mrow[1] + 8.f)) {
      #pragma unroll
      for (int qt = 0; qt < 2; ++qt) {
        float v = mx[qt];
        v = fmaxf(v, __shfl_xor(v, 16));
        v = fmaxf(v, __shfl_xor(v, 32));
        float nm = fmaxf(mrow[qt], v);
        float sc = __builtin_amdgcn_exp2f(mrow[qt] - nm);
        mrow[qt] = nm;
        lsum[qt] *= sc;
        #pragma unroll
        for (int dt = 0; dt < 4; ++dt)
          #pragma unroll
          for (int r = 0; r < 4; ++r) o[qt][dt][r] *= sc;
      }
    }

    // --- P = exp2(S - m), partial row-sum, pack to LDS as P^T[q][k] ---
    #pragma unroll
    for (int qt = 0; qt < 2; ++qt) {
      float part = 0.f;
      #pragma unroll
      for (int c = 0; c < 4; ++c) {
        f32x4 e;
        #pragma unroll
        for (int r = 0; r < 4; ++r) {
          e[r] = __builtin_amdgcn_exp2f(p[qt][c][r] - mrow[qt]);
          part += e[r];
        }
        union { f16x2 h2[2]; f16x4 h4; } u;
        u.h2[0] = cvt_pk(e[0], e[1]);
        u.h2[1] = cvt_pk(e[2], e[3]);
        *(f16x4*)&Pl[w][qt*16 + lc][c*16 + g*4] = u.h4;
      }
      lsum[qt] += part;
    }

    // --- O^T += V^T * P  (A = V^T rows = d, B = P^T cols = q) ---
    #pragma unroll
    for (int ch = 0; ch < 2; ++ch) {
      f16x8 pf[2];
      #pragma unroll
      for (int qt = 0; qt < 2; ++qt)
        pf[qt] = *(const f16x8*)((const char*)&Pl[w][qt*16 + lc][0] + ch*64 + g*16);
      #pragma unroll
      for (int dt = 0; dt < 4; ++dt) {
        const char* vbase = (const char*)&Vb[cur][0][0] + (dt*16 + lc) * 128;
        f16x8 vf = *(const f16x8*)(vbase + ((ch*64 + g*16) ^ ((lc & 7) << 4)));
        #pragma unroll
        for (int qt = 0; qt < 2; ++qt)
          o[qt][dt] = __builtin_amdgcn_mfma_f32_16x16x32_f16(vf, pf[qt], o[qt][dt], 0, 0, 0);
      }
    }

    __syncthreads();
    cur ^= 1;
  }

  // --- finalize: cross-group lsum reduce, divide, pack, store ---
  #pragma unroll
  for (int qt = 0; qt < 2; ++qt) {
    lsum[qt] += __shfl_xor(lsum[qt], 16);
    lsum[qt] += __shfl_xor(lsum[qt], 32);
    float inv = 1.f / lsum[qt];
    #pragma unroll
    for (int dt = 0; dt < 4; ++dt) {
      union { f16x2 h2[2]; f16x4 h4; } u;
      u.h2[0] = cvt_pk(o[qt][dt][0]*inv, o[qt][dt][1]*inv);
      u.h2[1] = cvt_pk(o[qt][dt][2]*inv, o[qt][dt][3]*inv);
      *(f16x4*)(ctx + (size_t)(b*SEQ + q0 + qt*16 + lc) * DMODEL + h*DK + dt*16 + g*4) = u.h4;
    }
  }
}

extern "C" void kernel_launch(void* const* d_in, const int* in_sizes, int n_in,
                              void* d_out, int out_size, void* d_ws, size_t ws_size,
                              hipStream_t stream) {
  const float* x    = (const float*)d_in[0];
  const int*   mask = (const int*)d_in[1];
  const float* Wqkv = (const float*)d_in[2];
  const float* bqkv = (const float*)d_in[3];
  const float* Wout = (const float*)d_in[4];
  const float* bout = (const float*)d_in[5];
  float* out = (float*)d_out;

  const size_t SZ_X    = (size_t)MTOT * DMODEL * 2;
  const size_t SZ_WQKV = (size_t)NQKV * DMODEL * 2;
  const size_t SZ_WOUT = (size_t)DMODEL * DMODEL * 2;
  const size_t SZ_QKV  = (size_t)BATCH * NHEADS * SEQ * DK * 2;
  const size_t NEED = SZ_X + SZ_WQKV + SZ_WOUT + 3*SZ_QKV + SZ_X;
  if (ws_size < NEED) return;

  char* p = (char*)d_ws;
  f16* xh    = (f16*)p; p += SZ_X;
  f16* Wqkvt = (f16*)p; p += SZ_WQKV;
  f16* Woutt = (f16*)p; p += SZ_WOUT;
  f16* Qh    = (f16*)p; p += SZ_QKV;
  f16* Kh    = (f16*)p; p += SZ_QKV;
  f16* Vth   = (f16*)p; p += SZ_QKV;
  f16* ctx   = (f16*)p; p += SZ_X;

  k_cvt<<<(MTOT*DMODEL)/(256*4), 256, 0, stream>>>(x, xh, MTOT*DMODEL);
  k_tcvt<<<dim3(NQKV/32, DMODEL/32), dim3(32,8), 0, stream>>>(Wqkv, Wqkvt, DMODEL, NQKV);
  k_tcvt<<<dim3(DMODEL/32, DMODEL/32), dim3(32,8), 0, stream>>>(Wout, Woutt, DMODEL, DMODEL);

  k_gemm<0><<<dim3(NQKV/128, MTOT/128), 256, 0, stream>>>(
      xh, Wqkvt, bqkv, Qh, Kh, Vth, nullptr, MTOT, NQKV, DMODEL);

  k_attn2<<<32 * 16, 256, 0, stream>>>(Qh, Kh, Vth, mask, ctx);

  k_gemm<1><<<dim3(DMODEL/128, MTOT/128), 256, 0, stream>>>(
      ctx, Woutt, bout, nullptr, nullptr, nullptr, out, MTOT, DMODEL, DMODEL);
}

// Round 4
// 149.221 us; speedup vs baseline: 2.0862x; 1.0334x over previous
//
#include <hip/hip_runtime.h>

typedef _Float16 f16;
typedef _Float16 f16x2 __attribute__((ext_vector_type(2)));
typedef _Float16 f16x4 __attribute__((ext_vector_type(4)));
typedef _Float16 f16x8 __attribute__((ext_vector_type(8)));
typedef float    f32x4 __attribute__((ext_vector_type(4)));
typedef int      i32x4 __attribute__((ext_vector_type(4)));

#define NHEADS 16
#define DK 64
#define BATCH 2
#define SEQ 2048
#define DMODEL 1024
#define MTOT (BATCH*SEQ)          // 4096
#define NQKV (3*DMODEL)           // 3072
#define LOG2E 1.44269504f
#define QSCALE (0.125f * LOG2E)   // fold 1/sqrt(dk) and log2(e) into Q
#define MASKVAL (-10000.0f * LOG2E)

__device__ inline f16x8 ld_f16x8_g(const f16* p) {
  return __builtin_bit_cast(f16x8, *reinterpret_cast<const i32x4*>(p));
}

__device__ inline f16x2 cvt_pk(float a, float b) {
  return __builtin_bit_cast(f16x2, __builtin_amdgcn_cvt_pkrtz(a, b));
}

__device__ inline void gl_lds16(const void* g, void* l) {
  __builtin_amdgcn_global_load_lds(
      (const __attribute__((address_space(1))) unsigned int*)g,
      (__attribute__((address_space(3))) unsigned int*)l, 16, 0, 0);
}

// ---------------- convert f32 -> f16, elementwise (n % 4 == 0) ----------------
__global__ void k_cvt(const float* __restrict__ in, f16* __restrict__ out, int n) {
  int i = (blockIdx.x * blockDim.x + threadIdx.x) * 4;
  if (i >= n) return;
  float4 v = *reinterpret_cast<const float4*>(in + i);
  f16x4 o = { (f16)v.x, (f16)v.y, (f16)v.z, (f16)v.w };
  *reinterpret_cast<f16x4*>(out + i) = o;
}

// ------- transpose + convert: in f32 [K][N] -> out f16 [N][K] (K,N % 32 == 0) -------
__global__ void k_tcvt(const float* __restrict__ in, f16* __restrict__ out, int K, int N) {
  __shared__ float tile[32][33];
  int k0 = blockIdx.y * 32, n0 = blockIdx.x * 32;
  int tx = threadIdx.x, ty = threadIdx.y;   // block (32,8)
  #pragma unroll
  for (int i = 0; i < 4; ++i)
    tile[ty + 8*i][tx] = in[(size_t)(k0 + ty + 8*i) * N + n0 + tx];
  __syncthreads();
  #pragma unroll
  for (int i = 0; i < 4; ++i)
    out[(size_t)(n0 + ty + 8*i) * K + k0 + tx] = (f16)tile[tx][ty + 8*i];
}

// ---------------- GEMM: C[M,N] = A[M,K](f16) * Bt[N,K]^T(f16) + bias ----------------
template<int EPI>
__global__ __launch_bounds__(256, 2) void k_gemm(
    const f16* __restrict__ A, const f16* __restrict__ Bt,
    const float* __restrict__ bias,
    f16* __restrict__ qo, f16* __restrict__ ko, f16* __restrict__ vto,
    float* __restrict__ outf, int M, int N, int K)
{
  __shared__ f16 As[128][72];
  __shared__ f16 Bs[128][72];
  const int m0 = blockIdx.y * 128, n0 = blockIdx.x * 128;
  const int t = threadIdx.x;
  const int l = t & 63, w = t >> 6;
  const int wr = w >> 1, wc = w & 1;
  const int lc = l & 15, lk = (l >> 4) * 8;

  f32x4 acc[4][4] = {};

  for (int kt = 0; kt < K; kt += 64) {
    #pragma unroll
    for (int it = 0; it < 4; ++it) {
      int idx = it * 256 + t;
      int row = idx >> 3, c8 = (idx & 7) * 8;
      *reinterpret_cast<i32x4*>(&As[row][c8]) =
        *reinterpret_cast<const i32x4*>(A + (size_t)(m0 + row) * K + kt + c8);
      *reinterpret_cast<i32x4*>(&Bs[row][c8]) =
        *reinterpret_cast<const i32x4*>(Bt + (size_t)(n0 + row) * K + kt + c8);
    }
    __syncthreads();
    #pragma unroll
    for (int ks = 0; ks < 64; ks += 32) {
      f16x8 af[4], bf[4];
      #pragma unroll
      for (int i = 0; i < 4; ++i)
        af[i] = __builtin_bit_cast(f16x8, *reinterpret_cast<i32x4*>(&As[wr*64 + i*16 + lc][ks + lk]));
      #pragma unroll
      for (int j = 0; j < 4; ++j)
        bf[j] = __builtin_bit_cast(f16x8, *reinterpret_cast<i32x4*>(&Bs[wc*64 + j*16 + lc][ks + lk]));
      #pragma unroll
      for (int i = 0; i < 4; ++i)
        #pragma unroll
        for (int j = 0; j < 4; ++j)
          acc[i][j] = __builtin_amdgcn_mfma_f32_16x16x32_f16(af[i], bf[j], acc[i][j], 0, 0, 0);
    }
    __syncthreads();
  }

  const int lr4 = (l >> 4) * 4;   // C/D: row = (l>>4)*4 + r, col = l&15
  #pragma unroll
  for (int i = 0; i < 4; ++i) {
    #pragma unroll
    for (int j = 0; j < 4; ++j) {
      int col = n0 + wc*64 + j*16 + lc;
      float bv = bias[col];
      #pragma unroll
      for (int r = 0; r < 4; ++r) {
        int row = m0 + wr*64 + i*16 + lr4 + r;
        float v = acc[i][j][r] + bv;
        if (EPI == 0) {
          int which = col >> 10, h = (col >> 6) & 15, d = col & 63;
          int b = row >> 11, s = row & (SEQ - 1);
          size_t bh = (size_t)(b * NHEADS + h);
          if (which == 0)      qo[(bh * SEQ + s) * DK + d] = (f16)(v * QSCALE);
          else if (which == 1) ko[(bh * SEQ + s) * DK + d] = (f16)v;
          else                 vto[(bh * DK + d) * SEQ + s] = (f16)v;
        } else {
          outf[(size_t)row * N + col] = v;
        }
      }
    }
  }
}

// ---------------- flash attention v3 ----------------
// 512 blocks; XCD-swizzled so each XCD owns 4 heads (K/V L2-resident per XCD).
// K/V^T TRIPLE-buffered in LDS via global_load_lds; counted vmcnt + raw barrier
// (T4): stage t+2 issued after the barrier, wait is vmcnt(4) not 0.
__global__ __launch_bounds__(256, 2) void k_attn3(
    const f16* __restrict__ Q, const f16* __restrict__ K,
    const f16* __restrict__ Vt, const int* __restrict__ mask,
    f16* __restrict__ ctx)
{
  __shared__ f16 Kb[3][64][64];
  __shared__ f16 Vb[3][64][64];
  __shared__ f16 Pl[4][32][72];

  // XCD-aware remap: assume bid%8 = XCD; give each XCD 4 whole heads.
  const int bid = blockIdx.x;
  const int xcd = bid & 7, slot = bid >> 3;        // slot in 0..63
  const int bh = xcd * 4 + (slot >> 4);            // 0..31
  const int qb = slot & 15;
  const int b  = bh >> 4, h = bh & (NHEADS - 1);
  const int t = threadIdx.x, l = t & 63, w = t >> 6;
  const int lc = l & 15, g = l >> 4;
  const int q0 = qb * 128 + w * 32;

  const f16* Qp = Q + (size_t)bh * SEQ * DK;
  const f16* Kp = K + (size_t)bh * SEQ * DK;
  const f16* Vp = Vt + (size_t)bh * DK * SEQ;
  const int* mp = mask + b * SEQ;

  // Q B-frags (col = q = lc, k-dim = d), kept in regs for the whole kernel
  f16x8 qf[2][2];
  #pragma unroll
  for (int qt = 0; qt < 2; ++qt)
    #pragma unroll
    for (int s = 0; s < 2; ++s)
      qf[qt][s] = ld_f16x8_g(Qp + (size_t)(q0 + qt*16 + lc) * DK + s*32 + g*8);

  f32x4 o[2][4] = {};                      // O^T acc: [q-tile][d-tile]
  float mrow[2] = {-3e38f, -3e38f};
  float lsum[2] = {0.f, 0.f};

  const int srow = l >> 3;                 // staging: row within 8-row stripe
  const int ssl  = ((l & 7) ^ srow) * 16;  // inverse-swizzled source 16B slot

  auto do_stage = [&](int buf, int kt) {
    #pragma unroll
    for (int p = 0; p < 2; ++p) {
      int r = p*32 + w*8 + srow;
      gl_lds16((const char*)Kp + (size_t)(kt + r) * (DK*2) + ssl,
               &Kb[buf][p*32 + w*8][0]);
      gl_lds16((const char*)Vp + (size_t)r * (SEQ*2) + (size_t)kt*2 + ssl,
               &Vb[buf][p*32 + w*8][0]);
    }
  };

  constexpr int NT = SEQ / 64;             // 32 k-tiles
  do_stage(0, 0);                          // prologue: 2 tiles in flight
  do_stage(1, 64);

  int cur = 0, nx = 2;                     // compute buf, stage-ahead buf
  for (int it = 0; it < NT; ++it) {
    // wait for stage(it); keep stage(it+1)'s 4 loads in flight (T4)
    if (it + 1 < NT) asm volatile("s_waitcnt vmcnt(4) lgkmcnt(0)" ::: "memory");
    else             asm volatile("s_waitcnt vmcnt(0) lgkmcnt(0)" ::: "memory");
    __builtin_amdgcn_s_barrier();
    asm volatile("" ::: "memory");
    if (it + 2 < NT) do_stage(nx, (it + 2) * 64);   // overwrites buf read in it-1

    const int kt = it * 64;

    // --- S^T = K * Q^T  (rows = k, cols = q) ---
    f32x4 p[2][4] = {};
    #pragma unroll
    for (int c = 0; c < 4; ++c) {
      const char* kbase = (const char*)&Kb[cur][0][0] + (c*16 + lc) * 128;
      f16x8 k0 = *(const f16x8*)(kbase + ((g*16)      ^ ((lc & 7) << 4)));
      f16x8 k1 = *(const f16x8*)(kbase + ((64 + g*16) ^ ((lc & 7) << 4)));
      #pragma unroll
      for (int qt = 0; qt < 2; ++qt) {
        p[qt][c] = __builtin_amdgcn_mfma_f32_16x16x32_f16(k0, qf[qt][0], p[qt][c], 0, 0, 0);
        p[qt][c] = __builtin_amdgcn_mfma_f32_16x16x32_f16(k1, qf[qt][1], p[qt][c], 0, 0, 0);
      }
    }

    // --- mask: replace masked k-rows with MASKVAL (lane's k = 16c + 4g + r) ---
    #pragma unroll
    for (int c = 0; c < 4; ++c) {
      int4 mv = *(const int4*)(mp + kt + c*16 + g*4);
      const int mi[4] = {mv.x, mv.y, mv.z, mv.w};
      #pragma unroll
      for (int r = 0; r < 4; ++r)
        if (mi[r] == 0) { p[0][c][r] = MASKVAL; p[1][c][r] = MASKVAL; }
    }

    // --- online softmax (per q-tile; defer-max T13, THR=8 on log2 scale) ---
    float mx[2];
    #pragma unroll
    for (int qt = 0; qt < 2; ++qt) {
      f32x4 m4 = p[qt][0];
      #pragma unroll
      for (int c = 1; c < 4; ++c)
        #pragma unroll
        for (int r = 0; r < 4; ++r) m4[r] = fmaxf(m4[r], p[qt][c][r]);
      mx[qt] = fmaxf(fmaxf(m4[0], m4[1]), fmaxf(m4[2], m4[3]));
    }

    if (!__all(mx[0] <= mrow[0] + 8.f && mx[1] <= mrow[1] + 8.f)) {
      #pragma unroll
      for (int qt = 0; qt < 2; ++qt) {
        float v = mx[qt];
        v = fmaxf(v, __shfl_xor(v, 16));
        v = fmaxf(v, __shfl_xor(v, 32));
        float nm = fmaxf(mrow[qt], v);
        float sc = __builtin_amdgcn_exp2f(mrow[qt] - nm);
        mrow[qt] = nm;
        lsum[qt] *= sc;
        #pragma unroll
        for (int dt = 0; dt < 4; ++dt)
          #pragma unroll
          for (int r = 0; r < 4; ++r) o[qt][dt][r] *= sc;
      }
    }

    // --- P = exp2(S - m), partial row-sum, pack to LDS as P^T[q][k] ---
    #pragma unroll
    for (int qt = 0; qt < 2; ++qt) {
      float part = 0.f;
      #pragma unroll
      for (int c = 0; c < 4; ++c) {
        f32x4 e;
        #pragma unroll
        for (int r = 0; r < 4; ++r) {
          e[r] = __builtin_amdgcn_exp2f(p[qt][c][r] - mrow[qt]);
          part += e[r];
        }
        union { f16x2 h2[2]; f16x4 h4; } u;
        u.h2[0] = cvt_pk(e[0], e[1]);
        u.h2[1] = cvt_pk(e[2], e[3]);
        *(f16x4*)&Pl[w][qt*16 + lc][c*16 + g*4] = u.h4;
      }
      lsum[qt] += part;
    }

    // --- O^T += V^T * P  (A = V^T rows = d, B = P^T cols = q) ---
    #pragma unroll
    for (int ch = 0; ch < 2; ++ch) {
      f16x8 pf[2];
      #pragma unroll
      for (int qt = 0; qt < 2; ++qt)
        pf[qt] = *(const f16x8*)((const char*)&Pl[w][qt*16 + lc][0] + ch*64 + g*16);
      #pragma unroll
      for (int dt = 0; dt < 4; ++dt) {
        const char* vbase = (const char*)&Vb[cur][0][0] + (dt*16 + lc) * 128;
        f16x8 vf = *(const f16x8*)(vbase + ((ch*64 + g*16) ^ ((lc & 7) << 4)));
        #pragma unroll
        for (int qt = 0; qt < 2; ++qt)
          o[qt][dt] = __builtin_amdgcn_mfma_f32_16x16x32_f16(vf, pf[qt], o[qt][dt], 0, 0, 0);
      }
    }

    cur = (cur == 2) ? 0 : cur + 1;
    nx  = (nx  == 2) ? 0 : nx  + 1;
  }

  // --- finalize: cross-group lsum reduce, divide, pack, store ---
  #pragma unroll
  for (int qt = 0; qt < 2; ++qt) {
    lsum[qt] += __shfl_xor(lsum[qt], 16);
    lsum[qt] += __shfl_xor(lsum[qt], 32);
    float inv = 1.f / lsum[qt];
    #pragma unroll
    for (int dt = 0; dt < 4; ++dt) {
      union { f16x2 h2[2]; f16x4 h4; } u;
      u.h2[0] = cvt_pk(o[qt][dt][0]*inv, o[qt][dt][1]*inv);
      u.h2[1] = cvt_pk(o[qt][dt][2]*inv, o[qt][dt][3]*inv);
      *(f16x4*)(ctx + (size_t)(b*SEQ + q0 + qt*16 + lc) * DMODEL + h*DK + dt*16 + g*4) = u.h4;
    }
  }
}

extern "C" void kernel_launch(void* const* d_in, const int* in_sizes, int n_in,
                              void* d_out, int out_size, void* d_ws, size_t ws_size,
                              hipStream_t stream) {
  const float* x    = (const float*)d_in[0];
  const int*   mask = (const int*)d_in[1];
  const float* Wqkv = (const float*)d_in[2];
  const float* bqkv = (const float*)d_in[3];
  const float* Wout = (const float*)d_in[4];
  const float* bout = (const float*)d_in[5];
  float* out = (float*)d_out;

  const size_t SZ_X    = (size_t)MTOT * DMODEL * 2;
  const size_t SZ_WQKV = (size_t)NQKV * DMODEL * 2;
  const size_t SZ_WOUT = (size_t)DMODEL * DMODEL * 2;
  const size_t SZ_QKV  = (size_t)BATCH * NHEADS * SEQ * DK * 2;
  const size_t NEED = SZ_X + SZ_WQKV + SZ_WOUT + 3*SZ_QKV + SZ_X;
  if (ws_size < NEED) return;

  char* p = (char*)d_ws;
  f16* xh    = (f16*)p; p += SZ_X;
  f16* Wqkvt = (f16*)p; p += SZ_WQKV;
  f16* Woutt = (f16*)p; p += SZ_WOUT;
  f16* Qh    = (f16*)p; p += SZ_QKV;
  f16* Kh    = (f16*)p; p += SZ_QKV;
  f16* Vth   = (f16*)p; p += SZ_QKV;
  f16* ctx   = (f16*)p; p += SZ_X;

  k_cvt<<<(MTOT*DMODEL)/(256*4), 256, 0, stream>>>(x, xh, MTOT*DMODEL);
  k_tcvt<<<dim3(NQKV/32, DMODEL/32), dim3(32,8), 0, stream>>>(Wqkv, Wqkvt, DMODEL, NQKV);
  k_tcvt<<<dim3(DMODEL/32, DMODEL/32), dim3(32,8), 0, stream>>>(Wout, Woutt, DMODEL, DMODEL);

  k_gemm<0><<<dim3(NQKV/128, MTOT/128), 256, 0, stream>>>(
      xh, Wqkvt, bqkv, Qh, Kh, Vth, nullptr, MTOT, NQKV, DMODEL);

  k_attn3<<<32 * 16, 256, 0, stream>>>(Qh, Kh, Vth, mask, ctx);

  k_gemm<1><<<dim3(DMODEL/128, MTOT/128), 256, 0, stream>>>(
      ctx, Woutt, bout, nullptr, nullptr, nullptr, out, MTOT, DMODEL, DMODEL);
}

// Round 5
// 142.812 us; speedup vs baseline: 2.1799x; 1.0449x over previous
//
#include <hip/hip_runtime.h>

typedef _Float16 f16;
typedef _Float16 f16x2 __attribute__((ext_vector_type(2)));
typedef _Float16 f16x4 __attribute__((ext_vector_type(4)));
typedef _Float16 f16x8 __attribute__((ext_vector_type(8)));
typedef float    f32x4 __attribute__((ext_vector_type(4)));
typedef int      i32x4 __attribute__((ext_vector_type(4)));

#define NHEADS 16
#define DK 64
#define BATCH 2
#define SEQ 2048
#define DMODEL 1024
#define MTOT (BATCH*SEQ)          // 4096
#define NQKV (3*DMODEL)           // 3072
#define LOG2E 1.44269504f
#define QSCALE (0.125f * LOG2E)   // fold 1/sqrt(dk) and log2(e) into Q
#define MASKVAL (-10000.0f * LOG2E)

__device__ inline f16x8 ld_f16x8_g(const f16* p) {
  return __builtin_bit_cast(f16x8, *reinterpret_cast<const i32x4*>(p));
}

__device__ inline f16x2 cvt_pk(float a, float b) {
  return __builtin_bit_cast(f16x2, __builtin_amdgcn_cvt_pkrtz(a, b));
}

__device__ inline void gl_lds16(const void* g, void* l) {
  __builtin_amdgcn_global_load_lds(
      (const __attribute__((address_space(1))) unsigned int*)g,
      (__attribute__((address_space(3))) unsigned int*)l, 16, 0, 0);
}

// ---------------- convert f32 -> f16, elementwise (n % 4 == 0) ----------------
__global__ void k_cvt(const float* __restrict__ in, f16* __restrict__ out, int n) {
  int i = (blockIdx.x * blockDim.x + threadIdx.x) * 4;
  if (i >= n) return;
  float4 v = *reinterpret_cast<const float4*>(in + i);
  f16x4 o = { (f16)v.x, (f16)v.y, (f16)v.z, (f16)v.w };
  *reinterpret_cast<f16x4*>(out + i) = o;
}

// ---------------- mask -> additive f32 bias in exp2 domain ----------------
__global__ void k_maskb(const int* __restrict__ mask, float* __restrict__ mb, int n) {
  int i = blockIdx.x * blockDim.x + threadIdx.x;
  if (i < n) mb[i] = mask[i] ? 0.f : MASKVAL;
}

// ------- transpose + convert: in f32 [K][N] -> out f16 [N][K] (K,N % 32 == 0) -------
__global__ void k_tcvt(const float* __restrict__ in, f16* __restrict__ out, int K, int N) {
  __shared__ float tile[32][33];
  int k0 = blockIdx.y * 32, n0 = blockIdx.x * 32;
  int tx = threadIdx.x, ty = threadIdx.y;   // block (32,8)
  #pragma unroll
  for (int i = 0; i < 4; ++i)
    tile[ty + 8*i][tx] = in[(size_t)(k0 + ty + 8*i) * N + n0 + tx];
  __syncthreads();
  #pragma unroll
  for (int i = 0; i < 4; ++i)
    out[(size_t)(n0 + ty + 8*i) * K + k0 + tx] = (f16)tile[tx][ty + 8*i];
}

// ---------------- GEMM: C[M,N] = A[M,K](f16) * Bt[N,K]^T(f16) + bias ----------------
template<int EPI>
__global__ __launch_bounds__(256, 2) void k_gemm(
    const f16* __restrict__ A, const f16* __restrict__ Bt,
    const float* __restrict__ bias,
    f16* __restrict__ qo, f16* __restrict__ ko, f16* __restrict__ vto,
    float* __restrict__ outf, int M, int N, int K)
{
  __shared__ f16 As[128][72];
  __shared__ f16 Bs[128][72];
  const int m0 = blockIdx.y * 128, n0 = blockIdx.x * 128;
  const int t = threadIdx.x;
  const int l = t & 63, w = t >> 6;
  const int wr = w >> 1, wc = w & 1;
  const int lc = l & 15, lk = (l >> 4) * 8;

  f32x4 acc[4][4] = {};

  for (int kt = 0; kt < K; kt += 64) {
    #pragma unroll
    for (int it = 0; it < 4; ++it) {
      int idx = it * 256 + t;
      int row = idx >> 3, c8 = (idx & 7) * 8;
      *reinterpret_cast<i32x4*>(&As[row][c8]) =
        *reinterpret_cast<const i32x4*>(A + (size_t)(m0 + row) * K + kt + c8);
      *reinterpret_cast<i32x4*>(&Bs[row][c8]) =
        *reinterpret_cast<const i32x4*>(Bt + (size_t)(n0 + row) * K + kt + c8);
    }
    __syncthreads();
    #pragma unroll
    for (int ks = 0; ks < 64; ks += 32) {
      f16x8 af[4], bf[4];
      #pragma unroll
      for (int i = 0; i < 4; ++i)
        af[i] = __builtin_bit_cast(f16x8, *reinterpret_cast<i32x4*>(&As[wr*64 + i*16 + lc][ks + lk]));
      #pragma unroll
      for (int j = 0; j < 4; ++j)
        bf[j] = __builtin_bit_cast(f16x8, *reinterpret_cast<i32x4*>(&Bs[wc*64 + j*16 + lc][ks + lk]));
      #pragma unroll
      for (int i = 0; i < 4; ++i)
        #pragma unroll
        for (int j = 0; j < 4; ++j)
          acc[i][j] = __builtin_amdgcn_mfma_f32_16x16x32_f16(af[i], bf[j], acc[i][j], 0, 0, 0);
    }
    __syncthreads();
  }

  const int lr4 = (l >> 4) * 4;   // C/D: row = (l>>4)*4 + r, col = l&15
  #pragma unroll
  for (int i = 0; i < 4; ++i) {
    #pragma unroll
    for (int j = 0; j < 4; ++j) {
      int col = n0 + wc*64 + j*16 + lc;
      float bv = bias[col];
      #pragma unroll
      for (int r = 0; r < 4; ++r) {
        int row = m0 + wr*64 + i*16 + lr4 + r;
        float v = acc[i][j][r] + bv;
        if (EPI == 0) {
          int which = col >> 10, h = (col >> 6) & 15, d = col & 63;
          int b = row >> 11, s = row & (SEQ - 1);
          size_t bh = (size_t)(b * NHEADS + h);
          if (which == 0)      qo[(bh * SEQ + s) * DK + d] = (f16)(v * QSCALE);
          else if (which == 1) ko[(bh * SEQ + s) * DK + d] = (f16)v;
          else {
            // V^T stored with kappa-permuted s within each 64-tile:
            // kappa(k) = (k&32) | ((k&12)<<1) | ((k&16)>>2) | (k&3)
            int sp = (s & ~63) | (s & 32) | ((s & 12) << 1) | ((s & 16) >> 2) | (s & 3);
            vto[(bh * DK + d) * SEQ + sp] = (f16)v;
          }
        } else {
          outf[(size_t)row * N + col] = v;
        }
      }
    }
  }
}

// ---------------- flash attention v4 ----------------
// 1024 blocks = 32 (b,h) * 32 q-blocks of 64; wave owns 16 q rows.
// LDS: K/V double-buffer only (32 KB) -> 4 blocks/CU. P stays in registers:
// PV k-slots relabeled via kappa-permuted V columns so B-frag = lane's own h4 regs.
// Mask folded into QK accumulator init (f32 bias, preloaded one iter ahead).
__global__ __launch_bounds__(256, 4) void k_attn4(
    const f16* __restrict__ Q, const f16* __restrict__ K,
    const f16* __restrict__ Vt, const float* __restrict__ mbias,
    f16* __restrict__ ctx)
{
  __shared__ f16 Kb[2][64][64];
  __shared__ f16 Vb[2][64][64];

  // XCD-aware remap: bid%8 = XCD; each XCD owns 4 whole heads.
  const int bid = blockIdx.x;
  const int xcd = bid & 7, slot = bid >> 3;        // slot 0..127
  const int bh = xcd * 4 + (slot >> 5);            // 0..31
  const int qb = slot & 31;
  const int b  = bh >> 4, h = bh & (NHEADS - 1);
  const int t = threadIdx.x, l = t & 63, w = t >> 6;
  const int lc = l & 15, g = l >> 4;
  const int q0 = qb * 64 + w * 16;

  const f16* Qp = Q + (size_t)bh * SEQ * DK;
  const f16* Kp = K + (size_t)bh * SEQ * DK;
  const f16* Vp = Vt + (size_t)bh * DK * SEQ;
  const float* mp = mbias + b * SEQ;

  // Q B-frags (col = q = lc), kept in regs
  f16x8 qf[2];
  #pragma unroll
  for (int s = 0; s < 2; ++s)
    qf[s] = ld_f16x8_g(Qp + (size_t)(q0 + lc) * DK + s*32 + g*8);

  f32x4 o[4] = {};            // O^T acc per d-tile
  float mrow = -3e38f;
  f32x4 ls4 = {0.f, 0.f, 0.f, 0.f};

  const int srow = l >> 3;                 // staging row within 8-row stripe
  const int ssl  = ((l & 7) ^ srow) * 16;  // inverse-swizzled source slot
  const int swz  = (lc & 7) << 4;          // read-side XOR

  auto do_stage = [&](int buf, int kt) {
    #pragma unroll
    for (int p = 0; p < 2; ++p) {
      int r = p*32 + w*8 + srow;
      gl_lds16((const char*)Kp + (size_t)(kt + r) * (DK*2) + ssl,
               &Kb[buf][p*32 + w*8][0]);
      gl_lds16((const char*)Vp + (size_t)r * (SEQ*2) + (size_t)kt*2 + ssl,
               &Vb[buf][p*32 + w*8][0]);
    }
  };

  constexpr int NT = SEQ / 64;
  do_stage(0, 0);

  float4 b4[4];
  #pragma unroll
  for (int c = 0; c < 4; ++c)
    b4[c] = *reinterpret_cast<const float4*>(mp + c*16 + g*4);

  for (int it = 0; it < NT; ++it) {
    __syncthreads();                         // vmcnt(0)+lgkmcnt(0)+barrier
    if (it + 1 < NT) do_stage((it + 1) & 1, (it + 1) * 64);

    // --- S^T = K * Q^T + maskbias (rows = k, cols = q) ---
    f32x4 p[4];
    #pragma unroll
    for (int c = 0; c < 4; ++c)
      p[c] = f32x4{b4[c].x, b4[c].y, b4[c].z, b4[c].w};
    const char* kb = (const char*)&Kb[it & 1][0][0];
    #pragma unroll
    for (int c = 0; c < 4; ++c) {
      const char* kr = kb + (c*16 + lc) * 128;
      f16x8 k0 = *(const f16x8*)(kr + ((g*16) ^ swz));
      f16x8 k1 = *(const f16x8*)(kr + ((64 + g*16) ^ swz));
      p[c] = __builtin_amdgcn_mfma_f32_16x16x32_f16(k0, qf[0], p[c], 0, 0, 0);
      p[c] = __builtin_amdgcn_mfma_f32_16x16x32_f16(k1, qf[1], p[c], 0, 0, 0);
    }

    // preload next tile's bias (covered by softmax+PV latency)
    if (it + 1 < NT) {
      const float* mn = mp + (it + 1) * 64;
      #pragma unroll
      for (int c = 0; c < 4; ++c)
        b4[c] = *reinterpret_cast<const float4*>(mn + c*16 + g*4);
    }

    // --- online softmax (defer-max T13, THR=8 in log2 domain) ---
    f32x4 m4 = p[0];
    #pragma unroll
    for (int c = 1; c < 4; ++c)
      #pragma unroll
      for (int r = 0; r < 4; ++r) m4[r] = fmaxf(m4[r], p[c][r]);
    float mx = fmaxf(fmaxf(m4[0], m4[1]), fmaxf(m4[2], m4[3]));

    if (!__all(mx <= mrow + 8.f)) {
      mx = fmaxf(mx, __shfl_xor(mx, 16));
      mx = fmaxf(mx, __shfl_xor(mx, 32));
      float nm = fmaxf(mrow, mx);
      float sc = __builtin_amdgcn_exp2f(mrow - nm);
      mrow = nm;
      #pragma unroll
      for (int r = 0; r < 4; ++r) ls4[r] *= sc;
      #pragma unroll
      for (int dt = 0; dt < 4; ++dt)
        #pragma unroll
        for (int r = 0; r < 4; ++r) o[dt][r] *= sc;
    }

    // --- P = exp2(S - m), vector row-sum, pack in-register ---
    f16x4 h4[4];
    #pragma unroll
    for (int c = 0; c < 4; ++c) {
      f32x4 e;
      #pragma unroll
      for (int r = 0; r < 4; ++r) e[r] = __builtin_amdgcn_exp2f(p[c][r] - mrow);
      #pragma unroll
      for (int r = 0; r < 4; ++r) ls4[r] += e[r];
      union { f16x2 h2[2]; f16x4 h4v; } u;
      u.h2[0] = cvt_pk(e[0], e[1]);
      u.h2[1] = cvt_pk(e[2], e[3]);
      h4[c] = u.h4v;
    }

    // --- O^T += V^T * P : B-frag is lane-local [h4[2ch] | h4[2ch+1]] ---
    const char* vb = (const char*)&Vb[it & 1][0][0];
    #pragma unroll
    for (int ch = 0; ch < 2; ++ch) {
      union { f16x4 q[2]; f16x8 v8; } upf;
      upf.q[0] = h4[2*ch]; upf.q[1] = h4[2*ch + 1];
      f16x8 pf = upf.v8;
      #pragma unroll
      for (int dt = 0; dt < 4; ++dt) {
        const char* vr = vb + (dt*16 + lc) * 128;
        f16x8 vf = *(const f16x8*)(vr + ((ch*64 + g*16) ^ swz));
        o[dt] = __builtin_amdgcn_mfma_f32_16x16x32_f16(vf, pf, o[dt], 0, 0, 0);
      }
    }
  }

  // --- finalize ---
  float s = (ls4[0] + ls4[1]) + (ls4[2] + ls4[3]);
  s += __shfl_xor(s, 16);
  s += __shfl_xor(s, 32);
  float inv = 1.f / s;
  #pragma unroll
  for (int dt = 0; dt < 4; ++dt) {
    union { f16x2 h2[2]; f16x4 h4v; } u;
    u.h2[0] = cvt_pk(o[dt][0]*inv, o[dt][1]*inv);
    u.h2[1] = cvt_pk(o[dt][2]*inv, o[dt][3]*inv);
    *(f16x4*)(ctx + (size_t)(b*SEQ + q0 + lc) * DMODEL + h*DK + dt*16 + g*4) = u.h4v;
  }
}

extern "C" void kernel_launch(void* const* d_in, const int* in_sizes, int n_in,
                              void* d_out, int out_size, void* d_ws, size_t ws_size,
                              hipStream_t stream) {
  const float* x    = (const float*)d_in[0];
  const int*   mask = (const int*)d_in[1];
  const float* Wqkv = (const float*)d_in[2];
  const float* bqkv = (const float*)d_in[3];
  const float* Wout = (const float*)d_in[4];
  const float* bout = (const float*)d_in[5];
  float* out = (float*)d_out;

  const size_t SZ_X    = (size_t)MTOT * DMODEL * 2;
  const size_t SZ_WQKV = (size_t)NQKV * DMODEL * 2;
  const size_t SZ_WOUT = (size_t)DMODEL * DMODEL * 2;
  const size_t SZ_QKV  = (size_t)BATCH * NHEADS * SEQ * DK * 2;
  const size_t SZ_MB   = (size_t)MTOT * 4 / 2;   // 2*2048 floats = 16KB
  const size_t NEED = SZ_X + SZ_WQKV + SZ_WOUT + 3*SZ_QKV + SZ_X + SZ_MB;
  if (ws_size < NEED) return;

  char* p = (char*)d_ws;
  f16* xh    = (f16*)p; p += SZ_X;
  f16* Wqkvt = (f16*)p; p += SZ_WQKV;
  f16* Woutt = (f16*)p; p += SZ_WOUT;
  f16* Qh    = (f16*)p; p += SZ_QKV;
  f16* Kh    = (f16*)p; p += SZ_QKV;
  f16* Vth   = (f16*)p; p += SZ_QKV;
  f16* ctx   = (f16*)p; p += SZ_X;
  float* mb  = (float*)p; p += SZ_MB;

  k_cvt<<<(MTOT*DMODEL)/(256*4), 256, 0, stream>>>(x, xh, MTOT*DMODEL);
  k_maskb<<<(BATCH*SEQ + 255)/256, 256, 0, stream>>>(mask, mb, BATCH*SEQ);
  k_tcvt<<<dim3(NQKV/32, DMODEL/32), dim3(32,8), 0, stream>>>(Wqkv, Wqkvt, DMODEL, NQKV);
  k_tcvt<<<dim3(DMODEL/32, DMODEL/32), dim3(32,8), 0, stream>>>(Wout, Woutt, DMODEL, DMODEL);

  k_gemm<0><<<dim3(NQKV/128, MTOT/128), 256, 0, stream>>>(
      xh, Wqkvt, bqkv, Qh, Kh, Vth, nullptr, MTOT, NQKV, DMODEL);

  k_attn4<<<32 * 32, 256, 0, stream>>>(Qh, Kh, Vth, mb, ctx);

  k_gemm<1><<<dim3(DMODEL/128, MTOT/128), 256, 0, stream>>>(
      ctx, Woutt, bout, nullptr, nullptr, nullptr, out, MTOT, DMODEL, DMODEL);
}